// Round 11
// baseline (109.030 us; speedup 1.0000x reference)
//
#include <hip/hip_runtime.h>
#include <hip/hip_bf16.h>
#include <cstddef>

// MoE gate: B,S,D,E,K = 4,4096,2048,64,2. N = 16384 tokens.
// out layout: dispatch [N][E][K] (2,097,152 f) | combine [N][E][K] | lbl | z
namespace {
constexpr int kD = 2048;
constexpr int kE = 64;
constexpr int kN = 16384;
constexpr size_t kDispatchFloats = (size_t)kN * kE * 2;  // 2,097,152
constexpr size_t kWsplitOff = 1024;  // float offset of W-split region in ws
}

typedef short short8_t __attribute__((ext_vector_type(8)));
typedef float f32x4 __attribute__((ext_vector_type(4)));

// ---------------------------------------------------------------------------
__global__ void zero_ws_kernel(float* __restrict__ ws) {
  ws[threadIdx.x] = 0.0f;  // 256 accumulator slots (129 used)
}

// fp32 -> 3 scaled bf16 splits: x ~= s1 + s2*2^-8 + s3*2^-16 (all normal bf16)
__device__ __forceinline__ void split3(float f, unsigned short& s1,
                                       unsigned short& s2, unsigned short& s3) {
  __hip_bfloat16 h1 = __float2bfloat16(f);
  float r1 = (f - __bfloat162float(h1)) * 256.0f;
  __hip_bfloat16 h2 = __float2bfloat16(r1);
  float r2 = (r1 - __bfloat162float(h2)) * 256.0f;
  __hip_bfloat16 h3 = __float2bfloat16(r2);
  s1 = __builtin_bit_cast(unsigned short, h1);
  s2 = __builtin_bit_cast(unsigned short, h2);
  s3 = __builtin_bit_cast(unsigned short, h3);
}

// ---------------------------------------------------------------------------
// Kernel A: pre-split W [64][2048] fp32 -> ws bf16 [3][64][2048] (768 KB).
// Runs every call (deterministic); 16384 threads x 8 floats.
__global__ __launch_bounds__(256)
void split_w_kernel(const float* __restrict__ W, unsigned short* __restrict__ wsp) {
  const int i = blockIdx.x * 256 + threadIdx.x;  // 0..16383
  const float4* src = reinterpret_cast<const float4*>(W) + i * 2;
  const float4 v0 = src[0], v1 = src[1];
  short8_t o1, o2, o3;
  unsigned short s1, s2, s3;
  split3(v0.x, s1, s2, s3); o1[0]=(short)s1; o2[0]=(short)s2; o3[0]=(short)s3;
  split3(v0.y, s1, s2, s3); o1[1]=(short)s1; o2[1]=(short)s2; o3[1]=(short)s3;
  split3(v0.z, s1, s2, s3); o1[2]=(short)s1; o2[2]=(short)s2; o3[2]=(short)s3;
  split3(v0.w, s1, s2, s3); o1[3]=(short)s1; o2[3]=(short)s2; o3[3]=(short)s3;
  split3(v1.x, s1, s2, s3); o1[4]=(short)s1; o2[4]=(short)s2; o3[4]=(short)s3;
  split3(v1.y, s1, s2, s3); o1[5]=(short)s1; o2[5]=(short)s2; o3[5]=(short)s3;
  split3(v1.z, s1, s2, s3); o1[6]=(short)s1; o2[6]=(short)s2; o3[6]=(short)s3;
  split3(v1.w, s1, s2, s3); o1[7]=(short)s1; o2[7]=(short)s2; o3[7]=(short)s3;
  *reinterpret_cast<short8_t*>(wsp + (size_t)0 * 131072 + i * 8) = o1;
  *reinterpret_cast<short8_t*>(wsp + (size_t)1 * 131072 + i * 8) = o2;
  *reinterpret_cast<short8_t*>(wsp + (size_t)2 * 131072 + i * 8) = o3;
}

// convert 16 floats (4x float4) -> 3 splits, store swizzled 16B cols into tile
__device__ __forceinline__ void conv_store(const float4* v,
                                           unsigned short (*dst)[64][64],
                                           int srow, int seg) {
  short8_t o1[2], o2[2], o3[2];
#pragma unroll
  for (int j = 0; j < 4; ++j) {
    const float4 f = v[j];
    const int ch = j >> 1, b0 = (j & 1) * 4;
    unsigned short s1, s2, s3;
    split3(f.x, s1, s2, s3); o1[ch][b0+0]=(short)s1; o2[ch][b0+0]=(short)s2; o3[ch][b0+0]=(short)s3;
    split3(f.y, s1, s2, s3); o1[ch][b0+1]=(short)s1; o2[ch][b0+1]=(short)s2; o3[ch][b0+1]=(short)s3;
    split3(f.z, s1, s2, s3); o1[ch][b0+2]=(short)s1; o2[ch][b0+2]=(short)s2; o3[ch][b0+2]=(short)s3;
    split3(f.w, s1, s2, s3); o1[ch][b0+3]=(short)s1; o2[ch][b0+3]=(short)s2; o3[ch][b0+3]=(short)s3;
  }
#pragma unroll
  for (int ch = 0; ch < 2; ++ch) {
    const int col = (seg * 2 + ch) ^ (srow & 7);
    *reinterpret_cast<short8_t*>(&dst[0][srow][col * 8]) = o1[ch];
    *reinterpret_cast<short8_t*>(&dst[1][srow][col * 8]) = o2[ch];
    *reinterpret_cast<short8_t*>(&dst[2][srow][col * 8]) = o3[ch];
  }
}

// ---------------------------------------------------------------------------
// Kernel B: partial logits. Grid 1024 = 256 tiles x 4 K-quarters (tile =
// bid&255 so a tile's 4 dq-blocks AND its gate block share an XCD/L2).
// Block 256 thr = 4 waves, wave = 32tok x 32exp quadrant. Only x goes through
// LDS (24 KB -> 4 blocks/CU); B-fragments of pre-split W load straight from
// global (L2-resident) into registers. Triple-split bf16 MFMA (r8-proven).
__global__ __launch_bounds__(256)
void logits_kernel(const float* __restrict__ x,
                   const unsigned short* __restrict__ wsp,
                   float* __restrict__ out) {
  __shared__ unsigned short xs[3][64][64];  // [split][token][k] 24 KB

  const int tid  = threadIdx.x;
  const int lane = tid & 63;
  const int wv   = __builtin_amdgcn_readfirstlane(tid >> 6);
  const int wr   = wv >> 1;        // token half
  const int wc   = wv & 1;         // expert half
  const int tile = blockIdx.x & 255;
  const int dq   = blockIdx.x >> 8;
  const int lrow = lane & 15;
  const int lk   = lane >> 4;

  // staging role: 4 threads per token row, 16 contiguous floats each
  const int row = tid >> 2, seg = tid & 3;
  const float4* __restrict__ bx = reinterpret_cast<const float4*>(x) +
      ((size_t)tile * 64 + row) * 512 + dq * 128 + seg * 4;

  f32x4 acc0[2][2], acc1[2][2], acc2[2][2];
  const f32x4 z4 = {0.0f, 0.0f, 0.0f, 0.0f};
#pragma unroll
  for (int a = 0; a < 2; ++a)
#pragma unroll
    for (int b = 0; b < 2; ++b) { acc0[a][b] = z4; acc1[a][b] = z4; acc2[a][b] = z4; }

  float4 vx[4];
#pragma unroll
  for (int j = 0; j < 4; ++j) vx[j] = bx[j];

  for (int c = 0; c < 8; ++c) {
    __syncthreads();                     // prev chunk's reads complete
    conv_store(vx, xs, row, seg);        // implicit vmcnt wait on vx
    __syncthreads();                     // tile ready
    if (c < 7) {                         // prefetch next chunk during MFMA
#pragma unroll
      for (int j = 0; j < 4; ++j) vx[j] = bx[(c + 1) * 16 + j];
    }
#pragma unroll
    for (int ks = 0; ks < 2; ++ks) {
      const int kc = ks * 4 + lk;        // 16B col 0..7 (pre-swizzle)
      short8_t a1[2], a2[2], a3[2], b1[2], b2[2], b3[2];
#pragma unroll
      for (int nt = 0; nt < 2; ++nt) {   // B-frags straight from global (L2)
        const int e = wc * 32 + nt * 16 + lrow;
        const size_t ko = (size_t)e * 2048 + dq * 512 + c * 64 + kc * 8;
        b1[nt] = *reinterpret_cast<const short8_t*>(wsp + 0 * 131072 + ko);
        b2[nt] = *reinterpret_cast<const short8_t*>(wsp + 1 * 131072 + ko);
        b3[nt] = *reinterpret_cast<const short8_t*>(wsp + 2 * 131072 + ko);
      }
#pragma unroll
      for (int mt = 0; mt < 2; ++mt) {   // A-frags from swizzled LDS
        const int r = wr * 32 + mt * 16 + lrow;
        const int cw = (kc ^ (r & 7)) * 8;
        a1[mt] = *reinterpret_cast<const short8_t*>(&xs[0][r][cw]);
        a2[mt] = *reinterpret_cast<const short8_t*>(&xs[1][r][cw]);
        a3[mt] = *reinterpret_cast<const short8_t*>(&xs[2][r][cw]);
      }
#pragma unroll
      for (int mt = 0; mt < 2; ++mt)
#pragma unroll
        for (int nt = 0; nt < 2; ++nt) {
          acc0[mt][nt] = __builtin_amdgcn_mfma_f32_16x16x32_bf16(a1[mt], b1[nt], acc0[mt][nt], 0, 0, 0);
          acc1[mt][nt] = __builtin_amdgcn_mfma_f32_16x16x32_bf16(a1[mt], b2[nt], acc1[mt][nt], 0, 0, 0);
          acc1[mt][nt] = __builtin_amdgcn_mfma_f32_16x16x32_bf16(a2[mt], b1[nt], acc1[mt][nt], 0, 0, 0);
          acc2[mt][nt] = __builtin_amdgcn_mfma_f32_16x16x32_bf16(a1[mt], b3[nt], acc2[mt][nt], 0, 0, 0);
          acc2[mt][nt] = __builtin_amdgcn_mfma_f32_16x16x32_bf16(a3[mt], b1[nt], acc2[mt][nt], 0, 0, 0);
          acc2[mt][nt] = __builtin_amdgcn_mfma_f32_16x16x32_bf16(a2[mt], b2[nt], acc2[mt][nt], 0, 0, 0);
        }
    }
  }

  // epilogue: L = acc0 + acc1*2^-8 + acc2*2^-16 -> token's own partial slots
  const float k8 = 1.0f / 256.0f, k16 = 1.0f / 65536.0f;
  float* __restrict__ base = out + ((dq < 2) ? (size_t)0 : kDispatchFloats);
#pragma unroll
  for (int mt = 0; mt < 2; ++mt)
#pragma unroll
    for (int r = 0; r < 4; ++r) {
      const int trow = wr * 32 + mt * 16 + lk * 4 + r;  // C row = (lane>>4)*4+r
      const size_t n = (size_t)tile * 64 + trow;
      float* __restrict__ dst =
          base + n * 128 + (dq & 1) * 64 + wc * 32 + lrow;  // C col = lane&15
#pragma unroll
      for (int nt = 0; nt < 2; ++nt)
        dst[nt * 16] = acc0[mt][nt][r] + acc1[mt][nt][r] * k8 + acc2[mt][nt][r] * k16;
    }
}

// ---------------------------------------------------------------------------
// Kernel C: sum 4 partials -> logits, softmax, top-2, outputs, losses.
// 256 blocks x 256 threads, 64 tokens/block; tile t on the same XCD as its
// logits blocks (bid%8 match) -> partial reads are L2 hits.
__global__ __launch_bounds__(256)
void gate_kernel(float* __restrict__ out, float* __restrict__ ws) {
  __shared__ float lg[64][65];
  __shared__ int ti0[64], ti1[64];
  __shared__ float tv0[64], tv1[64], tz2[64];
  const int tid  = threadIdx.x;
  const int tile = blockIdx.x;

  float* __restrict__ outd = out + (size_t)tile * 8192;
  float* __restrict__ outc = out + kDispatchFloats + (size_t)tile * 8192;
  const float4* __restrict__ d4 = reinterpret_cast<const float4*>(outd);
  const float4* __restrict__ c4 = reinterpret_cast<const float4*>(outc);

  const int tq = tid >> 4, q = tid & 15;
#pragma unroll
  for (int k = 0; k < 4; ++k) {
    const int t = k * 16 + tq;
    const float4 a = d4[t * 32 + q];
    const float4 b = d4[t * 32 + 16 + q];
    const float4 c = c4[t * 32 + q];
    const float4 d = c4[t * 32 + 16 + q];
    lg[t][q * 4 + 0] = a.x + b.x + c.x + d.x;
    lg[t][q * 4 + 1] = a.y + b.y + c.y + d.y;
    lg[t][q * 4 + 2] = a.z + b.z + c.z + d.z;
    lg[t][q * 4 + 3] = a.w + b.w + c.w + d.w;
  }
  __syncthreads();

  if (tid < 64) {
    float v0 = -INFINITY, v1 = -INFINITY;
    int i0 = 0, i1 = 0;
    for (int e = 0; e < kE; ++e) {
      const float l = lg[tid][e];
      if (l > v0) { v1 = v0; i1 = i0; v0 = l; i0 = e; }
      else if (l > v1) { v1 = l; i1 = e; }
    }
    const float m = v0;
    float s = 0.0f;
    for (int e = 0; e < kE; ++e) s += __expf(lg[tid][e] - m);
    const float rs = 1.0f / s;
    float zexp = 0.0f;
    for (int e = 0; e < kE; ++e) zexp += __expf(__expf(lg[tid][e] - m) * rs);
    const float z = logf(zexp);
    ti0[tid] = i0; ti1[tid] = i1;
    tv0[tid] = rs;                    // exp(v0-m)*rs with v0==m
    tv1[tid] = __expf(v1 - m) * rs;
    tz2[tid] = z * z;
  }
  __syncthreads();

  if (tid < kE) {
    float g = 0.0f, cnt = 0.0f;
    for (int t = 0; t < 64; ++t) {
      if (ti0[t] == tid) { g += tv0[t]; cnt += 1.0f; }
      if (ti1[t] == tid) { g += tv1[t]; cnt += 1.0f; }
    }
    atomicAdd(&ws[tid], g);
    atomicAdd(&ws[kE + tid], cnt);
    float z2 = tz2[tid];
    for (int off = 32; off; off >>= 1) z2 += __shfl_down(z2, off);
    if (tid == 0) atomicAdd(&ws[2 * kE], z2);
  }

  {
    const int t = tid >> 2, sub = tid & 3;
    const int i0 = ti0[t], i1 = ti1[t];
    const float v0 = tv0[t], v1 = tv1[t];
    float4* __restrict__ dp = reinterpret_cast<float4*>(outd) + t * 32;
    float4* __restrict__ cp = reinterpret_cast<float4*>(outc) + t * 32;
#pragma unroll
    for (int j = 0; j < 8; ++j) {
      const int qq = sub * 8 + j;
      const int e0 = qq * 2, e1 = qq * 2 + 1;
      const float d0v = (e0 == i0 || e0 == i1) ? 1.0f : 0.0f;
      const float d1v = (e1 == i0 || e1 == i1) ? 1.0f : 0.0f;
      const float c0 = (e0 == i0) ? v0 : ((e0 == i1) ? v1 : 0.0f);
      const float c1 = (e1 == i0) ? v0 : ((e1 == i1) ? v1 : 0.0f);
      dp[qq] = make_float4(d0v, 0.0f, d1v, 0.0f);
      cp[qq] = make_float4(c0, 0.0f, c1, 0.0f);
    }
  }
}

// ---------------------------------------------------------------------------
__global__ void finalize_kernel(const float* __restrict__ ws,
                                float* __restrict__ out) {
  const int e = threadIdx.x;  // 64 threads
  float prod = ws[e] * ws[kE + e];
  for (int off = 32; off; off >>= 1) prod += __shfl_down(prod, off);
  if (e == 0) {
    const size_t base = kDispatchFloats * 2;
    const float invN = 1.0f / (float)kN;
    out[base]     = prod * ((float)kE * invN * invN);  // load_balancing_loss
    out[base + 1] = ws[2 * kE] * invN;                 // router_z_loss
  }
}

// ---------------------------------------------------------------------------
extern "C" void kernel_launch(void* const* d_in, const int* in_sizes, int n_in,
                              void* d_out, int out_size, void* d_ws,
                              size_t ws_size, hipStream_t stream) {
  const float* x = (const float*)d_in[0];  // [4,4096,2048] fp32
  const float* W = (const float*)d_in[1];  // [64,2048] fp32
  float* out = (float*)d_out;
  float* ws = (float*)d_ws;
  unsigned short* wsp = (unsigned short*)(ws + kWsplitOff);

  zero_ws_kernel<<<1, 256, 0, stream>>>(ws);
  split_w_kernel<<<64, 256, 0, stream>>>(W, wsp);
  logits_kernel<<<1024, 256, 0, stream>>>(x, wsp, out);
  gate_kernel<<<256, 256, 0, stream>>>(out, ws);
  finalize_kernel<<<1, kE, 0, stream>>>(ws, out);
}

// Round 12
// 79.384 us; speedup vs baseline: 1.3735x; 1.3735x over previous
//
#include <hip/hip_runtime.h>
#include <hip/hip_bf16.h>
#include <cstddef>

// MoE gate: B,S,D,E,K = 4,4096,2048,64,2. N = 16384 tokens.
// out layout: dispatch [N][E][K] (2,097,152 f) | combine [N][E][K] | lbl | z
namespace {
constexpr int kD = 2048;
constexpr int kE = 64;
constexpr int kN = 16384;
constexpr size_t kDispatchFloats = (size_t)kN * kE * 2;  // 2,097,152
constexpr size_t kWsplitOff = 1024;  // float offset of W-image region in ws
}

typedef short short8_t __attribute__((ext_vector_type(8)));
typedef float f32x4 __attribute__((ext_vector_type(4)));

// ---------------------------------------------------------------------------
__global__ void zero_ws_kernel(float* __restrict__ ws) {
  ws[threadIdx.x] = 0.0f;  // 256 accumulator slots (129 used)
}

// fp32 -> 3 scaled bf16 splits: x ~= s1 + s2*2^-8 + s3*2^-16 (all normal bf16)
__device__ __forceinline__ void split3(float f, unsigned short& s1,
                                       unsigned short& s2, unsigned short& s3) {
  __hip_bfloat16 h1 = __float2bfloat16(f);
  float r1 = (f - __bfloat162float(h1)) * 256.0f;
  __hip_bfloat16 h2 = __float2bfloat16(r1);
  float r2 = (r1 - __bfloat162float(h2)) * 256.0f;
  __hip_bfloat16 h3 = __float2bfloat16(r2);
  s1 = __builtin_bit_cast(unsigned short, h1);
  s2 = __builtin_bit_cast(unsigned short, h2);
  s3 = __builtin_bit_cast(unsigned short, h3);
}

// ---------------------------------------------------------------------------
// Kernel A: pre-split W into the exact swizzled LDS tile image.
// Image: per (dq,c) a [3][64][64]-short tile (24576 B); position
// [s][row][cs8*8+j] holds Wsplit_s[row][(cs8 ^ (row&7))*8 + j]  -- so a
// linear global_load_lds copy reproduces the swizzled LDS tile verbatim.
__global__ __launch_bounds__(256)
void split_w_kernel(const float* __restrict__ W, unsigned short* __restrict__ img) {
  const int t   = blockIdx.x * 256 + threadIdx.x;  // 0..16383
  const int dq  = t >> 12;
  const int c   = (t >> 9) & 7;
  const int row = (t >> 3) & 63;
  const int cs8 = t & 7;
  const int co  = cs8 ^ (row & 7);
  const float* src = W + (size_t)row * kD + dq * 512 + c * 64 + co * 8;
  const float4 v0 = *reinterpret_cast<const float4*>(src);
  const float4 v1 = *reinterpret_cast<const float4*>(src + 4);
  short8_t o1, o2, o3;
  unsigned short s1, s2, s3;
  split3(v0.x, s1, s2, s3); o1[0]=(short)s1; o2[0]=(short)s2; o3[0]=(short)s3;
  split3(v0.y, s1, s2, s3); o1[1]=(short)s1; o2[1]=(short)s2; o3[1]=(short)s3;
  split3(v0.z, s1, s2, s3); o1[2]=(short)s1; o2[2]=(short)s2; o3[2]=(short)s3;
  split3(v0.w, s1, s2, s3); o1[3]=(short)s1; o2[3]=(short)s2; o3[3]=(short)s3;
  split3(v1.x, s1, s2, s3); o1[4]=(short)s1; o2[4]=(short)s2; o3[4]=(short)s3;
  split3(v1.y, s1, s2, s3); o1[5]=(short)s1; o2[5]=(short)s2; o3[5]=(short)s3;
  split3(v1.z, s1, s2, s3); o1[6]=(short)s1; o2[6]=(short)s2; o3[6]=(short)s3;
  split3(v1.w, s1, s2, s3); o1[7]=(short)s1; o2[7]=(short)s2; o3[7]=(short)s3;
  unsigned short* dst = img + (size_t)(dq * 8 + c) * 12288 + row * 64 + cs8 * 8;
  *reinterpret_cast<short8_t*>(dst + 0 * 4096) = o1;
  *reinterpret_cast<short8_t*>(dst + 1 * 4096) = o2;
  *reinterpret_cast<short8_t*>(dst + 2 * 4096) = o3;
}

// convert 16 floats -> 3 splits, store swizzled 16B cols into x tile
__device__ __forceinline__ void conv_store4(float4 f0, float4 f1, float4 f2,
                                            float4 f3,
                                            unsigned short (*dst)[64][64],
                                            int srow, int seg) {
  const float4 v[4] = {f0, f1, f2, f3};
  short8_t o1[2], o2[2], o3[2];
#pragma unroll
  for (int j = 0; j < 4; ++j) {
    const float4 f = v[j];
    const int ch = j >> 1, b0 = (j & 1) * 4;
    unsigned short s1, s2, s3;
    split3(f.x, s1, s2, s3); o1[ch][b0+0]=(short)s1; o2[ch][b0+0]=(short)s2; o3[ch][b0+0]=(short)s3;
    split3(f.y, s1, s2, s3); o1[ch][b0+1]=(short)s1; o2[ch][b0+1]=(short)s2; o3[ch][b0+1]=(short)s3;
    split3(f.z, s1, s2, s3); o1[ch][b0+2]=(short)s1; o2[ch][b0+2]=(short)s2; o3[ch][b0+2]=(short)s3;
    split3(f.w, s1, s2, s3); o1[ch][b0+3]=(short)s1; o2[ch][b0+3]=(short)s2; o3[ch][b0+3]=(short)s3;
  }
#pragma unroll
  for (int ch = 0; ch < 2; ++ch) {
    const int col = (seg * 2 + ch) ^ (srow & 7);
    *reinterpret_cast<short8_t*>(&dst[0][srow][col * 8]) = o1[ch];
    *reinterpret_cast<short8_t*>(&dst[1][srow][col * 8]) = o2[ch];
    *reinterpret_cast<short8_t*>(&dst[2][srow][col * 8]) = o3[ch];
  }
}

// ---------------------------------------------------------------------------
// Kernel B: partial logits. Grid 1024 = 256 tiles x 4 K-quarters; 256 thr =
// 4 waves, wave = 32tok x 32exp quadrant; BK=64, 8 chunks. Per chunk:
//   W tile: 6x global_load_lds DMA from pre-swizzled image (no VALU/VGPR)
//   x tile: reg-prefetched fp32 -> split3 -> swizzled LDS store
//   counted s_waitcnt vmcnt(4) + raw s_barrier: W-DMA drained, x-prefetch
//   (4 loads, issued AFTER the 6 DMAs; sched_barrier pins order) stays in
//   flight across the barrier. x-prefetch index wraps (c+1)&7 so the vmcnt
//   count is uniform on the last iteration.
__global__ __launch_bounds__(256)
void logits_kernel(const float* __restrict__ x,
                   const unsigned short* __restrict__ wimg,
                   float* __restrict__ out) {
  __shared__ unsigned short xs[3][64][64];  // x tile,  24 KB
  __shared__ unsigned short wt[3][64][64];  // W tile,  24 KB

  const int tid  = threadIdx.x;
  const int lane = tid & 63;
  const int wv   = __builtin_amdgcn_readfirstlane(tid >> 6);
  const int wr   = wv >> 1;        // token half
  const int wc   = wv & 1;         // expert half
  const int tile = blockIdx.x & 255;
  const int dq   = blockIdx.x >> 8;
  const int lrow = lane & 15;
  const int lk   = lane >> 4;

  const int row = tid >> 2, seg = tid & 3;
  const float4* __restrict__ bx = reinterpret_cast<const float4*>(x) +
      ((size_t)tile * 64 + row) * 512 + dq * 128 + seg * 4;
  const unsigned short* __restrict__ wbase =
      wimg + (size_t)dq * 8 * 12288 + tid * 8;
  unsigned short* wtf = &wt[0][0][0];

  f32x4 acc0[2][2], acc1[2][2], acc2[2][2];
  const f32x4 z4 = {0.0f, 0.0f, 0.0f, 0.0f};
#pragma unroll
  for (int a = 0; a < 2; ++a)
#pragma unroll
    for (int b = 0; b < 2; ++b) { acc0[a][b] = z4; acc1[a][b] = z4; acc2[a][b] = z4; }

  float4 vx0 = bx[0], vx1 = bx[1], vx2 = bx[2], vx3 = bx[3];

  for (int c = 0; c < 8; ++c) {
    // 1. W-tile DMA for chunk c (6 x 16B/thread), oldest in vmcnt queue
    const unsigned short* wsrc = wbase + (size_t)c * 12288;
#pragma unroll
    for (int i = 0; i < 6; ++i)
      __builtin_amdgcn_global_load_lds(
          (const __attribute__((address_space(1))) void*)(wsrc + i * 2048),
          (__attribute__((address_space(3))) void*)(wtf + i * 2048 + wv * 512),
          16, 0, 0);
    __builtin_amdgcn_sched_barrier(0);  // pin: x-loads must issue AFTER DMAs
    // 2. consume x(c) regs; issue x(c+1) prefetch (wraps on last iter)
    const float4 xa = vx0, xb = vx1, xc2 = vx2, xd = vx3;
    const int cn = (c + 1) & 7;
    vx0 = bx[cn * 16 + 0]; vx1 = bx[cn * 16 + 1];
    vx2 = bx[cn * 16 + 2]; vx3 = bx[cn * 16 + 3];
    // 3. convert + swizzled LDS store of x(c)
    conv_store4(xa, xb, xc2, xd, xs, row, seg);
    // 4. W-DMA + ds_writes drained; x(c+1) stays in flight across barrier
    asm volatile("s_waitcnt vmcnt(4) lgkmcnt(0)" ::: "memory");
    __builtin_amdgcn_sched_barrier(0);
    __builtin_amdgcn_s_barrier();
    __builtin_amdgcn_sched_barrier(0);
    // 5. MFMA phase (LDS only)
#pragma unroll
    for (int ks = 0; ks < 2; ++ks) {
      const int kc = ks * 4 + lk;
      short8_t a1[2], a2[2], a3[2], b1[2], b2[2], b3[2];
#pragma unroll
      for (int nt = 0; nt < 2; ++nt) {
        const int e = wc * 32 + nt * 16 + lrow;
        const int cw = (kc ^ (e & 7)) * 8;
        b1[nt] = *reinterpret_cast<const short8_t*>(&wt[0][e][cw]);
        b2[nt] = *reinterpret_cast<const short8_t*>(&wt[1][e][cw]);
        b3[nt] = *reinterpret_cast<const short8_t*>(&wt[2][e][cw]);
      }
#pragma unroll
      for (int mt = 0; mt < 2; ++mt) {
        const int r = wr * 32 + mt * 16 + lrow;
        const int cw = (kc ^ (r & 7)) * 8;
        a1[mt] = *reinterpret_cast<const short8_t*>(&xs[0][r][cw]);
        a2[mt] = *reinterpret_cast<const short8_t*>(&xs[1][r][cw]);
        a3[mt] = *reinterpret_cast<const short8_t*>(&xs[2][r][cw]);
      }
#pragma unroll
      for (int mt = 0; mt < 2; ++mt)
#pragma unroll
        for (int nt = 0; nt < 2; ++nt) {
          acc0[mt][nt] = __builtin_amdgcn_mfma_f32_16x16x32_bf16(a1[mt], b1[nt], acc0[mt][nt], 0, 0, 0);
          acc1[mt][nt] = __builtin_amdgcn_mfma_f32_16x16x32_bf16(a1[mt], b2[nt], acc1[mt][nt], 0, 0, 0);
          acc1[mt][nt] = __builtin_amdgcn_mfma_f32_16x16x32_bf16(a2[mt], b1[nt], acc1[mt][nt], 0, 0, 0);
          acc2[mt][nt] = __builtin_amdgcn_mfma_f32_16x16x32_bf16(a1[mt], b3[nt], acc2[mt][nt], 0, 0, 0);
          acc2[mt][nt] = __builtin_amdgcn_mfma_f32_16x16x32_bf16(a3[mt], b1[nt], acc2[mt][nt], 0, 0, 0);
          acc2[mt][nt] = __builtin_amdgcn_mfma_f32_16x16x32_bf16(a2[mt], b2[nt], acc2[mt][nt], 0, 0, 0);
        }
    }
    __builtin_amdgcn_sched_barrier(0);
    __builtin_amdgcn_s_barrier();  // all reads of this chunk done everywhere
  }

  // epilogue: L = acc0 + acc1*2^-8 + acc2*2^-16 -> token's own partial slots
  const float k8 = 1.0f / 256.0f, k16 = 1.0f / 65536.0f;
  float* __restrict__ base = out + ((dq < 2) ? (size_t)0 : kDispatchFloats);
#pragma unroll
  for (int mt = 0; mt < 2; ++mt)
#pragma unroll
    for (int r = 0; r < 4; ++r) {
      const int trow = wr * 32 + mt * 16 + lk * 4 + r;  // C row = (lane>>4)*4+r
      const size_t n = (size_t)tile * 64 + trow;
      float* __restrict__ dst =
          base + n * 128 + (dq & 1) * 64 + wc * 32 + lrow;  // C col = lane&15
#pragma unroll
      for (int nt = 0; nt < 2; ++nt)
        dst[nt * 16] = acc0[mt][nt][r] + acc1[mt][nt][r] * k8 + acc2[mt][nt][r] * k16;
    }
}

// ---------------------------------------------------------------------------
// Kernel C: sum 4 partials -> logits, softmax, top-2, outputs, losses.
__global__ __launch_bounds__(256)
void gate_kernel(float* __restrict__ out, float* __restrict__ ws) {
  __shared__ float lg[64][65];
  __shared__ int ti0[64], ti1[64];
  __shared__ float tv0[64], tv1[64], tz2[64];
  const int tid  = threadIdx.x;
  const int tile = blockIdx.x;

  float* __restrict__ outd = out + (size_t)tile * 8192;
  float* __restrict__ outc = out + kDispatchFloats + (size_t)tile * 8192;
  const float4* __restrict__ d4 = reinterpret_cast<const float4*>(outd);
  const float4* __restrict__ c4 = reinterpret_cast<const float4*>(outc);

  const int tq = tid >> 4, q = tid & 15;
#pragma unroll
  for (int k = 0; k < 4; ++k) {
    const int t = k * 16 + tq;
    const float4 a = d4[t * 32 + q];
    const float4 b = d4[t * 32 + 16 + q];
    const float4 c = c4[t * 32 + q];
    const float4 d = c4[t * 32 + 16 + q];
    lg[t][q * 4 + 0] = a.x + b.x + c.x + d.x;
    lg[t][q * 4 + 1] = a.y + b.y + c.y + d.y;
    lg[t][q * 4 + 2] = a.z + b.z + c.z + d.z;
    lg[t][q * 4 + 3] = a.w + b.w + c.w + d.w;
  }
  __syncthreads();

  if (tid < 64) {
    float v0 = -INFINITY, v1 = -INFINITY;
    int i0 = 0, i1 = 0;
    for (int e = 0; e < kE; ++e) {
      const float l = lg[tid][e];
      if (l > v0) { v1 = v0; i1 = i0; v0 = l; i0 = e; }
      else if (l > v1) { v1 = l; i1 = e; }
    }
    const float m = v0;
    float s = 0.0f;
    for (int e = 0; e < kE; ++e) s += __expf(lg[tid][e] - m);
    const float rs = 1.0f / s;
    float zexp = 0.0f;
    for (int e = 0; e < kE; ++e) zexp += __expf(__expf(lg[tid][e] - m) * rs);
    const float z = logf(zexp);
    ti0[tid] = i0; ti1[tid] = i1;
    tv0[tid] = rs;                    // exp(v0-m)*rs with v0==m
    tv1[tid] = __expf(v1 - m) * rs;
    tz2[tid] = z * z;
  }
  __syncthreads();

  if (tid < kE) {
    float g = 0.0f, cnt = 0.0f;
    for (int t = 0; t < 64; ++t) {
      if (ti0[t] == tid) { g += tv0[t]; cnt += 1.0f; }
      if (ti1[t] == tid) { g += tv1[t]; cnt += 1.0f; }
    }
    atomicAdd(&ws[tid], g);
    atomicAdd(&ws[kE + tid], cnt);
    float z2 = tz2[tid];
    for (int off = 32; off; off >>= 1) z2 += __shfl_down(z2, off);
    if (tid == 0) atomicAdd(&ws[2 * kE], z2);
  }

  {
    const int t = tid >> 2, sub = tid & 3;
    const int i0 = ti0[t], i1 = ti1[t];
    const float v0 = tv0[t], v1 = tv1[t];
    float4* __restrict__ dp = reinterpret_cast<float4*>(outd) + t * 32;
    float4* __restrict__ cp = reinterpret_cast<float4*>(outc) + t * 32;
#pragma unroll
    for (int j = 0; j < 8; ++j) {
      const int qq = sub * 8 + j;
      const int e0 = qq * 2, e1 = qq * 2 + 1;
      const float d0v = (e0 == i0 || e0 == i1) ? 1.0f : 0.0f;
      const float d1v = (e1 == i0 || e1 == i1) ? 1.0f : 0.0f;
      const float c0 = (e0 == i0) ? v0 : ((e0 == i1) ? v1 : 0.0f);
      const float c1 = (e1 == i0) ? v0 : ((e1 == i1) ? v1 : 0.0f);
      dp[qq] = make_float4(d0v, 0.0f, d1v, 0.0f);
      cp[qq] = make_float4(c0, 0.0f, c1, 0.0f);
    }
  }
}

// ---------------------------------------------------------------------------
__global__ void finalize_kernel(const float* __restrict__ ws,
                                float* __restrict__ out) {
  const int e = threadIdx.x;  // 64 threads
  float prod = ws[e] * ws[kE + e];
  for (int off = 32; off; off >>= 1) prod += __shfl_down(prod, off);
  if (e == 0) {
    const size_t base = kDispatchFloats * 2;
    const float invN = 1.0f / (float)kN;
    out[base]     = prod * ((float)kE * invN * invN);  // load_balancing_loss
    out[base + 1] = ws[2 * kE] * invN;                 // router_z_loss
  }
}

// ---------------------------------------------------------------------------
extern "C" void kernel_launch(void* const* d_in, const int* in_sizes, int n_in,
                              void* d_out, int out_size, void* d_ws,
                              size_t ws_size, hipStream_t stream) {
  const float* x = (const float*)d_in[0];  // [4,4096,2048] fp32
  const float* W = (const float*)d_in[1];  // [64,2048] fp32
  float* out = (float*)d_out;
  float* ws = (float*)d_ws;
  unsigned short* wimg = (unsigned short*)(ws + kWsplitOff);

  zero_ws_kernel<<<1, 256, 0, stream>>>(ws);
  split_w_kernel<<<64, 256, 0, stream>>>(W, wimg);
  logits_kernel<<<1024, 256, 0, stream>>>(x, wimg, out);
  gate_kernel<<<256, 256, 0, stream>>>(out, ws);
  finalize_kernel<<<1, kE, 0, stream>>>(ws, out);
}

// Round 13
// 73.286 us; speedup vs baseline: 1.4877x; 1.0832x over previous
//
#include <hip/hip_runtime.h>
#include <hip/hip_bf16.h>
#include <cstddef>

// MoE gate: B,S,D,E,K = 4,4096,2048,64,2. N = 16384 tokens.
// out layout: dispatch [N][E][K] (2,097,152 f) | combine [N][E][K] | lbl | z
namespace {
constexpr int kD = 2048;
constexpr int kE = 64;
constexpr int kN = 16384;
constexpr size_t kDispatchFloats = (size_t)kN * kE * 2;  // 2,097,152
constexpr size_t kWsplitOff = 1024;  // float offset of W-image region in ws
}

typedef short short8_t __attribute__((ext_vector_type(8)));
typedef float f32x4 __attribute__((ext_vector_type(4)));

// ---------------------------------------------------------------------------
__global__ void zero_ws_kernel(float* __restrict__ ws) {
  ws[threadIdx.x] = 0.0f;  // 256 accumulator slots (129 used)
}

// fp32 -> 3 scaled bf16 splits: x ~= s1 + s2*2^-8 + s3*2^-16 (all normal bf16)
__device__ __forceinline__ void split3(float f, unsigned short& s1,
                                       unsigned short& s2, unsigned short& s3) {
  __hip_bfloat16 h1 = __float2bfloat16(f);
  float r1 = (f - __bfloat162float(h1)) * 256.0f;
  __hip_bfloat16 h2 = __float2bfloat16(r1);
  float r2 = (r1 - __bfloat162float(h2)) * 256.0f;
  __hip_bfloat16 h3 = __float2bfloat16(r2);
  s1 = __builtin_bit_cast(unsigned short, h1);
  s2 = __builtin_bit_cast(unsigned short, h2);
  s3 = __builtin_bit_cast(unsigned short, h3);
}

// ---------------------------------------------------------------------------
// Kernel A: pre-split W into the exact swizzled LDS tile image (r12-proven).
// Per (dq,c): [3][64][64]-short tile; [s][row][cs8*8+j] holds
// Wsplit_s[row][(cs8 ^ (row&7))*8 + j] so a linear DMA reproduces the tile.
__global__ __launch_bounds__(256)
void split_w_kernel(const float* __restrict__ W, unsigned short* __restrict__ img) {
  const int t   = blockIdx.x * 256 + threadIdx.x;  // 0..16383
  const int dq  = t >> 12;
  const int c   = (t >> 9) & 7;
  const int row = (t >> 3) & 63;
  const int cs8 = t & 7;
  const int co  = cs8 ^ (row & 7);
  const float* src = W + (size_t)row * kD + dq * 512 + c * 64 + co * 8;
  const float4 v0 = *reinterpret_cast<const float4*>(src);
  const float4 v1 = *reinterpret_cast<const float4*>(src + 4);
  short8_t o1, o2, o3;
  unsigned short s1, s2, s3;
  split3(v0.x, s1, s2, s3); o1[0]=(short)s1; o2[0]=(short)s2; o3[0]=(short)s3;
  split3(v0.y, s1, s2, s3); o1[1]=(short)s1; o2[1]=(short)s2; o3[1]=(short)s3;
  split3(v0.z, s1, s2, s3); o1[2]=(short)s1; o2[2]=(short)s2; o3[2]=(short)s3;
  split3(v0.w, s1, s2, s3); o1[3]=(short)s1; o2[3]=(short)s2; o3[3]=(short)s3;
  split3(v1.x, s1, s2, s3); o1[4]=(short)s1; o2[4]=(short)s2; o3[4]=(short)s3;
  split3(v1.y, s1, s2, s3); o1[5]=(short)s1; o2[5]=(short)s2; o3[5]=(short)s3;
  split3(v1.z, s1, s2, s3); o1[6]=(short)s1; o2[6]=(short)s2; o3[6]=(short)s3;
  split3(v1.w, s1, s2, s3); o1[7]=(short)s1; o2[7]=(short)s2; o3[7]=(short)s3;
  unsigned short* dst = img + (size_t)(dq * 8 + c) * 12288 + row * 64 + cs8 * 8;
  *reinterpret_cast<short8_t*>(dst + 0 * 4096) = o1;
  *reinterpret_cast<short8_t*>(dst + 1 * 4096) = o2;
  *reinterpret_cast<short8_t*>(dst + 2 * 4096) = o3;
}

// convert 8 floats (2x float4) -> one short8 per split, store swizzled
__device__ __forceinline__ void conv_store8(float4 a, float4 b,
                                            unsigned short (*dst)[64][64],
                                            int row, int seg) {
  short8_t o1, o2, o3;
  unsigned short s1, s2, s3;
  split3(a.x, s1, s2, s3); o1[0]=(short)s1; o2[0]=(short)s2; o3[0]=(short)s3;
  split3(a.y, s1, s2, s3); o1[1]=(short)s1; o2[1]=(short)s2; o3[1]=(short)s3;
  split3(a.z, s1, s2, s3); o1[2]=(short)s1; o2[2]=(short)s2; o3[2]=(short)s3;
  split3(a.w, s1, s2, s3); o1[3]=(short)s1; o2[3]=(short)s2; o3[3]=(short)s3;
  split3(b.x, s1, s2, s3); o1[4]=(short)s1; o2[4]=(short)s2; o3[4]=(short)s3;
  split3(b.y, s1, s2, s3); o1[5]=(short)s1; o2[5]=(short)s2; o3[5]=(short)s3;
  split3(b.z, s1, s2, s3); o1[6]=(short)s1; o2[6]=(short)s2; o3[6]=(short)s3;
  split3(b.w, s1, s2, s3); o1[7]=(short)s1; o2[7]=(short)s2; o3[7]=(short)s3;
  const int col = seg ^ (row & 7);
  *reinterpret_cast<short8_t*>(&dst[0][row][col * 8]) = o1;
  *reinterpret_cast<short8_t*>(&dst[1][row][col * 8]) = o2;
  *reinterpret_cast<short8_t*>(&dst[2][row][col * 8]) = o3;
}

// ---------------------------------------------------------------------------
// Kernel B: partial logits. Grid 1024 = 256 tiles x 4 K-quarters.
// 512 thr = 8 waves: (wr tok-half, wc exp-half, kh k-half-of-chunk) -> per-wave
// MFMA work halves vs r12 and waves/CU doubles to 24 (same 48 KB LDS).
// Per chunk: 3x global_load_lds W-DMA (pre-swizzled image) + reg-prefetched x
// -> split3 -> swizzled LDS store; counted s_waitcnt vmcnt(2) keeps the 2
// x-prefetch loads in flight across the barrier. kh-half accumulators merge
// once at the end through the then-dead xs tile.
__global__ __launch_bounds__(512)
void logits_kernel(const float* __restrict__ x,
                   const unsigned short* __restrict__ wimg,
                   float* __restrict__ out) {
  __shared__ unsigned short xs[3][64][64];  // x tile, 24 KB (reused for merge)
  __shared__ unsigned short wt[3][64][64];  // W tile, 24 KB

  const int tid  = threadIdx.x;
  const int lane = tid & 63;
  const int wv   = __builtin_amdgcn_readfirstlane(tid >> 6);  // 0..7
  const int wr   = wv >> 2;        // token half
  const int wc   = (wv >> 1) & 1;  // expert half
  const int kh   = wv & 1;         // k-half within chunk (16B cols 0-3 / 4-7)
  const int tile = blockIdx.x & 255;
  const int dq   = blockIdx.x >> 8;
  const int lrow = lane & 15;
  const int lk   = lane >> 4;

  // staging role: 8 threads per token row, 8 contiguous floats each
  const int row = tid >> 3, seg = tid & 7;
  const float4* __restrict__ bx = reinterpret_cast<const float4*>(x) +
      ((size_t)tile * 64 + row) * 512 + dq * 128 + seg * 2;
  const unsigned short* __restrict__ wbase =
      wimg + (size_t)dq * 8 * 12288 + tid * 8;
  unsigned short* wtf = &wt[0][0][0];

  f32x4 acc0[2][2], acc1[2][2], acc2[2][2];
  const f32x4 z4 = {0.0f, 0.0f, 0.0f, 0.0f};
#pragma unroll
  for (int a = 0; a < 2; ++a)
#pragma unroll
    for (int b = 0; b < 2; ++b) { acc0[a][b] = z4; acc1[a][b] = z4; acc2[a][b] = z4; }

  float4 vx0 = bx[0], vx1 = bx[1];

  for (int c = 0; c < 8; ++c) {
    // 1. W-tile DMA for chunk c (3 x 16B/thread at 512 thr), oldest in queue
    const unsigned short* wsrc = wbase + (size_t)c * 12288;
#pragma unroll
    for (int i = 0; i < 3; ++i)
      __builtin_amdgcn_global_load_lds(
          (const __attribute__((address_space(1))) void*)(wsrc + i * 4096),
          (__attribute__((address_space(3))) void*)(wtf + i * 4096 + wv * 512),
          16, 0, 0);
    __builtin_amdgcn_sched_barrier(0);  // pin: x-loads issue AFTER DMAs
    // 2. consume x(c) regs; issue x(c+1) prefetch (wraps -> uniform vmcnt)
    const float4 xa = vx0, xb = vx1;
    const int cn = (c + 1) & 7;
    vx0 = bx[cn * 16 + 0];
    vx1 = bx[cn * 16 + 1];
    // 3. convert + swizzled LDS store of x(c)
    conv_store8(xa, xb, xs, row, seg);
    // 4. W-DMA + ds_writes drained; x(c+1) (2 loads) stays in flight
    asm volatile("s_waitcnt vmcnt(2) lgkmcnt(0)" ::: "memory");
    __builtin_amdgcn_sched_barrier(0);
    __builtin_amdgcn_s_barrier();
    __builtin_amdgcn_sched_barrier(0);
    // 5. MFMA phase: this wave's k-half only (kc in 0-3 or 4-7)
    {
      const int kc = kh * 4 + lk;
      short8_t a1[2], a2[2], a3[2], b1[2], b2[2], b3[2];
#pragma unroll
      for (int nt = 0; nt < 2; ++nt) {
        const int e = wc * 32 + nt * 16 + lrow;
        const int cw = (kc ^ (e & 7)) * 8;
        b1[nt] = *reinterpret_cast<const short8_t*>(&wt[0][e][cw]);
        b2[nt] = *reinterpret_cast<const short8_t*>(&wt[1][e][cw]);
        b3[nt] = *reinterpret_cast<const short8_t*>(&wt[2][e][cw]);
      }
#pragma unroll
      for (int mt = 0; mt < 2; ++mt) {
        const int r = wr * 32 + mt * 16 + lrow;
        const int cw = (kc ^ (r & 7)) * 8;
        a1[mt] = *reinterpret_cast<const short8_t*>(&xs[0][r][cw]);
        a2[mt] = *reinterpret_cast<const short8_t*>(&xs[1][r][cw]);
        a3[mt] = *reinterpret_cast<const short8_t*>(&xs[2][r][cw]);
      }
#pragma unroll
      for (int mt = 0; mt < 2; ++mt)
#pragma unroll
        for (int nt = 0; nt < 2; ++nt) {
          acc0[mt][nt] = __builtin_amdgcn_mfma_f32_16x16x32_bf16(a1[mt], b1[nt], acc0[mt][nt], 0, 0, 0);
          acc1[mt][nt] = __builtin_amdgcn_mfma_f32_16x16x32_bf16(a1[mt], b2[nt], acc1[mt][nt], 0, 0, 0);
          acc1[mt][nt] = __builtin_amdgcn_mfma_f32_16x16x32_bf16(a2[mt], b1[nt], acc1[mt][nt], 0, 0, 0);
          acc2[mt][nt] = __builtin_amdgcn_mfma_f32_16x16x32_bf16(a1[mt], b3[nt], acc2[mt][nt], 0, 0, 0);
          acc2[mt][nt] = __builtin_amdgcn_mfma_f32_16x16x32_bf16(a3[mt], b1[nt], acc2[mt][nt], 0, 0, 0);
          acc2[mt][nt] = __builtin_amdgcn_mfma_f32_16x16x32_bf16(a2[mt], b2[nt], acc2[mt][nt], 0, 0, 0);
        }
    }
    __builtin_amdgcn_sched_barrier(0);
    __builtin_amdgcn_s_barrier();  // all reads of this chunk done everywhere
  }

  // --- merge k-halves through the now-dead xs tile, then write partials ----
  const float k8 = 1.0f / 256.0f, k16 = 1.0f / 65536.0f;
  float* __restrict__ mbuf = reinterpret_cast<float*>(&xs[0][0][0]);  // [64][65]
  if (kh == 1) {
#pragma unroll
    for (int mt = 0; mt < 2; ++mt)
#pragma unroll
      for (int nt = 0; nt < 2; ++nt)
#pragma unroll
        for (int r = 0; r < 4; ++r) {
          const int trow = wr * 32 + mt * 16 + lk * 4 + r;
          const int col  = wc * 32 + nt * 16 + lrow;
          mbuf[trow * 65 + col] =
              acc0[mt][nt][r] + acc1[mt][nt][r] * k8 + acc2[mt][nt][r] * k16;
        }
  }
  __syncthreads();
  if (kh == 0) {
    float* __restrict__ base = out + ((dq < 2) ? (size_t)0 : kDispatchFloats);
#pragma unroll
    for (int mt = 0; mt < 2; ++mt)
#pragma unroll
      for (int r = 0; r < 4; ++r) {
        const int trow = wr * 32 + mt * 16 + lk * 4 + r;  // C row=(lane>>4)*4+r
        const size_t n = (size_t)tile * 64 + trow;
        float* __restrict__ dst =
            base + n * 128 + (dq & 1) * 64 + wc * 32 + lrow;  // C col=lane&15
#pragma unroll
        for (int nt = 0; nt < 2; ++nt) {
          const int col = wc * 32 + nt * 16 + lrow;
          dst[nt * 16] = acc0[mt][nt][r] + acc1[mt][nt][r] * k8 +
                         acc2[mt][nt][r] * k16 + mbuf[trow * 65 + col];
        }
      }
  }
}

// ---------------------------------------------------------------------------
// Kernel C: sum 4 partials -> logits, softmax, top-2, outputs, losses.
__global__ __launch_bounds__(256)
void gate_kernel(float* __restrict__ out, float* __restrict__ ws) {
  __shared__ float lg[64][65];
  __shared__ int ti0[64], ti1[64];
  __shared__ float tv0[64], tv1[64], tz2[64];
  const int tid  = threadIdx.x;
  const int tile = blockIdx.x;

  float* __restrict__ outd = out + (size_t)tile * 8192;
  float* __restrict__ outc = out + kDispatchFloats + (size_t)tile * 8192;
  const float4* __restrict__ d4 = reinterpret_cast<const float4*>(outd);
  const float4* __restrict__ c4 = reinterpret_cast<const float4*>(outc);

  const int tq = tid >> 4, q = tid & 15;
#pragma unroll
  for (int k = 0; k < 4; ++k) {
    const int t = k * 16 + tq;
    const float4 a = d4[t * 32 + q];
    const float4 b = d4[t * 32 + 16 + q];
    const float4 c = c4[t * 32 + q];
    const float4 d = c4[t * 32 + 16 + q];
    lg[t][q * 4 + 0] = a.x + b.x + c.x + d.x;
    lg[t][q * 4 + 1] = a.y + b.y + c.y + d.y;
    lg[t][q * 4 + 2] = a.z + b.z + c.z + d.z;
    lg[t][q * 4 + 3] = a.w + b.w + c.w + d.w;
  }
  __syncthreads();

  if (tid < 64) {
    float v0 = -INFINITY, v1 = -INFINITY;
    int i0 = 0, i1 = 0;
    for (int e = 0; e < kE; ++e) {
      const float l = lg[tid][e];
      if (l > v0) { v1 = v0; i1 = i0; v0 = l; i0 = e; }
      else if (l > v1) { v1 = l; i1 = e; }
    }
    const float m = v0;
    float s = 0.0f;
    for (int e = 0; e < kE; ++e) s += __expf(lg[tid][e] - m);
    const float rs = 1.0f / s;
    float zexp = 0.0f;
    for (int e = 0; e < kE; ++e) zexp += __expf(__expf(lg[tid][e] - m) * rs);
    const float z = logf(zexp);
    ti0[tid] = i0; ti1[tid] = i1;
    tv0[tid] = rs;                    // exp(v0-m)*rs with v0==m
    tv1[tid] = __expf(v1 - m) * rs;
    tz2[tid] = z * z;
  }
  __syncthreads();

  if (tid < kE) {
    float g = 0.0f, cnt = 0.0f;
    for (int t = 0; t < 64; ++t) {
      if (ti0[t] == tid) { g += tv0[t]; cnt += 1.0f; }
      if (ti1[t] == tid) { g += tv1[t]; cnt += 1.0f; }
    }
    atomicAdd(&ws[tid], g);
    atomicAdd(&ws[kE + tid], cnt);
    float z2 = tz2[tid];
    for (int off = 32; off; off >>= 1) z2 += __shfl_down(z2, off);
    if (tid == 0) atomicAdd(&ws[2 * kE], z2);
  }

  {
    const int t = tid >> 2, sub = tid & 3;
    const int i0 = ti0[t], i1 = ti1[t];
    const float v0 = tv0[t], v1 = tv1[t];
    float4* __restrict__ dp = reinterpret_cast<float4*>(outd) + t * 32;
    float4* __restrict__ cp = reinterpret_cast<float4*>(outc) + t * 32;
#pragma unroll
    for (int j = 0; j < 8; ++j) {
      const int qq = sub * 8 + j;
      const int e0 = qq * 2, e1 = qq * 2 + 1;
      const float d0v = (e0 == i0 || e0 == i1) ? 1.0f : 0.0f;
      const float d1v = (e1 == i0 || e1 == i1) ? 1.0f : 0.0f;
      const float c0 = (e0 == i0) ? v0 : ((e0 == i1) ? v1 : 0.0f);
      const float c1 = (e1 == i0) ? v0 : ((e1 == i1) ? v1 : 0.0f);
      dp[qq] = make_float4(d0v, 0.0f, d1v, 0.0f);
      cp[qq] = make_float4(c0, 0.0f, c1, 0.0f);
    }
  }
}

// ---------------------------------------------------------------------------
__global__ void finalize_kernel(const float* __restrict__ ws,
                                float* __restrict__ out) {
  const int e = threadIdx.x;  // 64 threads
  float prod = ws[e] * ws[kE + e];
  for (int off = 32; off; off >>= 1) prod += __shfl_down(prod, off);
  if (e == 0) {
    const size_t base = kDispatchFloats * 2;
    const float invN = 1.0f / (float)kN;
    out[base]     = prod * ((float)kE * invN * invN);  // load_balancing_loss
    out[base + 1] = ws[2 * kE] * invN;                 // router_z_loss
  }
}

// ---------------------------------------------------------------------------
extern "C" void kernel_launch(void* const* d_in, const int* in_sizes, int n_in,
                              void* d_out, int out_size, void* d_ws,
                              size_t ws_size, hipStream_t stream) {
  const float* x = (const float*)d_in[0];  // [4,4096,2048] fp32
  const float* W = (const float*)d_in[1];  // [64,2048] fp32
  float* out = (float*)d_out;
  float* ws = (float*)d_ws;
  unsigned short* wimg = (unsigned short*)(ws + kWsplitOff);

  zero_ws_kernel<<<1, 256, 0, stream>>>(ws);
  split_w_kernel<<<64, 256, 0, stream>>>(W, wimg);
  logits_kernel<<<1024, 512, 0, stream>>>(x, wimg, out);
  gate_kernel<<<256, 256, 0, stream>>>(out, ws);
  finalize_kernel<<<1, kE, 0, stream>>>(ws, out);
}